// Round 11
// baseline (221.137 us; speedup 1.0000x reference)
//
#include <hip/hip_runtime.h>

typedef short v8s __attribute__((ext_vector_type(8)));
typedef short v4s __attribute__((ext_vector_type(4)));
typedef float v4f __attribute__((ext_vector_type(4)));
typedef unsigned uint2v __attribute__((ext_vector_type(2)));
typedef unsigned uint4v __attribute__((ext_vector_type(4)));
typedef unsigned short u16;

#define NSEQ 2048
#define CDIM 768
#define NH   16
#define DH   48
#define DP   64
#define MROWS 4096      // B*N
#define N3C  2304
#define BH   32         // B*H

#if __has_builtin(__builtin_amdgcn_exp2f)
#define EXP2(x) __builtin_amdgcn_exp2f(x)
#else
#define EXP2(x) exp2f(x)
#endif
#if __has_builtin(__builtin_amdgcn_rcpf)
#define RCP(x) __builtin_amdgcn_rcpf(x)
#else
#define RCP(x) (1.0f/(x))
#endif

#if __has_builtin(__builtin_amdgcn_permlane32_swap) && __has_builtin(__builtin_amdgcn_permlane16_swap)
#define HAVE_PERMSWAP 1
#endif

__device__ __forceinline__ u16 f2bf(float f){
  unsigned u = __float_as_uint(f);
  u += 0x7FFFu + ((u>>16)&1u);      // RNE; inputs finite
  return (u16)(u>>16);
}

#if __has_builtin(__builtin_amdgcn_cvt_pk_bf16_f32)
typedef __bf16 bf16x2_t __attribute__((ext_vector_type(2)));
__device__ __forceinline__ unsigned pkbf(float a, float b){   // [lo=a, hi=b], RNE, 1 inst
  bf16x2_t r = __builtin_amdgcn_cvt_pk_bf16_f32(a, b);
  return __builtin_bit_cast(unsigned, r);
}
#else
__device__ __forceinline__ unsigned pkbf(float a, float b){   // [lo=a, hi=b] bf16 pair, RNE
  unsigned x = __float_as_uint(a), y = __float_as_uint(b);
  x += 0x7FFFu + ((x>>16)&1u);
  y += 0x7FFFu + ((y>>16)&1u);
  return (x>>16) | (y & 0xFFFF0000u);
}
#endif

__device__ __forceinline__ void load_lds16(const u16* g, u16* l){
  __builtin_amdgcn_global_load_lds((const __attribute__((address_space(1))) void*)g,
                                   (__attribute__((address_space(3))) void*)l, 16, 0, 0);
}

// ---------------- K0: fused convert (x,qkv_w,proj_w -> bf16) + Q/K pad init ----------------
#define XN8  (MROWS*CDIM/8)                     // 393216
#define WN8  (N3C*CDIM/8)                       // 221184
#define PN8  (CDIM*CDIM/8)                      // 73728
#define CONVB ((XN8+WN8+PN8)/256)               // 2688 blocks
__global__ __launch_bounds__(256) void prep(const float* __restrict__ x, const float* __restrict__ w,
                                            const float* __restrict__ pw, u16* __restrict__ dst,
                                            u16* __restrict__ q, u16* __restrict__ k){
  int bid = blockIdx.x;
  if (bid < CONVB){
    int i = bid*256 + threadIdx.x;
    const float* src;
    if (i < XN8)            src = x  + (size_t)i*8;
    else if (i < XN8+WN8)   src = w  + (size_t)(i - XN8)*8;
    else                    src = pw + (size_t)(i - XN8 - WN8)*8;
    v4f f0 = ((const v4f*)src)[0];
    v4f f1 = ((const v4f*)src)[1];
    v8s o;
#pragma unroll
    for (int j = 0; j < 4; j++) ((u16*)&o)[j]   = f2bf(f0[j]);
#pragma unroll
    for (int j = 0; j < 4; j++) ((u16*)&o)[4+j] = f2bf(f1[j]);
    ((v8s*)dst)[i] = o;
  } else {
    int idx = (bid - CONVB)*256 + threadIdx.x;  // 512 blocks -> 131072 threads
    v8s z = (v8s){0,0,0,0,0,0,0,0};
    int r = idx >> 1, half = idx & 1;           // Q/K: 65536 rows, 2x16B pad per row
    *(v8s*)(q + (size_t)r*DP + DH + half*8) = z;
    *(v8s*)(k + (size_t)r*DP + DH + half*8) = z;
  }
}

// ================= K1: qkv GEMM, m97 structure (round-4 version) =================
__global__ __launch_bounds__(256) void qkv_gemm(const u16* __restrict__ x, const u16* __restrict__ w,
                                                const float* __restrict__ bias,
                                                u16* __restrict__ q, u16* __restrict__ k, u16* __restrict__ v){
  __shared__ __align__(16) u16 As[128*32];
  __shared__ __align__(16) u16 Bs[128*32];
  const int wave = threadIdx.x >> 6;
  const int lane = threadIdx.x & 63;
  const int l15  = lane & 15;
  const int quad = lane >> 4;
  const int wm = wave & 1, wn = wave >> 1;
  const int m0 = blockIdx.x*128, n0 = blockIdx.y*128;

  const int srow = lane >> 2;
  const int sg   = (lane & 3) ^ ((lane >> 3) & 3);
  const int sgoff = sg*8;

  v4f acc[4][4];
#pragma unroll
  for (int i = 0; i < 4; i++)
#pragma unroll
    for (int j = 0; j < 4; j++) acc[i][j] = (v4f){0.f,0.f,0.f,0.f};

  const int sig = (l15 >> 1) & 3;

  for (int kt = 0; kt < CDIM/32; kt++){
    const int k0 = kt*32;
    __syncthreads();
#pragma unroll
    for (int j = 0; j < 2; j++){
      int c = wave*2 + j;
      int r = c*16 + srow;
      load_lds16(x + (size_t)(m0 + r)*CDIM + k0 + sgoff, &As[c*512]);
      load_lds16(w + (size_t)(n0 + r)*CDIM + k0 + sgoff, &Bs[c*512]);
    }
    __syncthreads();

    v8s af[4], bf[4];
#pragma unroll
    for (int t = 0; t < 4; t++){
      int ra = wm*64 + t*16 + l15;
      af[t] = *(const v8s*)(&As[ra*32 + ((quad ^ sig)<<3)]);
      int rb = wn*64 + t*16 + l15;
      bf[t] = *(const v8s*)(&Bs[rb*32 + ((quad ^ sig)<<3)]);
    }
#pragma unroll
    for (int ti = 0; ti < 4; ti++)
#pragma unroll
      for (int tj = 0; tj < 4; tj++)
        acc[ti][tj] = __builtin_amdgcn_mfma_f32_16x16x32_bf16(af[ti], bf[tj], acc[ti][tj], 0, 0, 0);
  }

  const float QS = 0.2082540589f;   // 1/sqrt(48) * log2(e)
#pragma unroll
  for (int tj = 0; tj < 4; tj++){
    const int c = n0 + wn*64 + tj*16 + l15;
    const float bv = bias[c];
    const int t = c / CDIM;
    const int rem = c - t*CDIM;
    const int h = rem / DH;
    const int d = rem - h*DH;
#pragma unroll
    for (int ti = 0; ti < 4; ti++){
#pragma unroll
      for (int r = 0; r < 4; r++){
        int m = m0 + wm*64 + ti*16 + quad*4 + r;
        int b_ = m >> 11;
        int n  = m & (NSEQ-1);
        float val = acc[ti][tj][r] + bv;
        if (t == 0) val *= QS;
        u16 o  = f2bf(val);
        int bhn = b_*NH + h;
        if (t == 0)      q[((size_t)bhn*NSEQ + n)*DP + d] = o;
        else if (t == 1) k[((size_t)bhn*NSEQ + n)*DP + d] = o;
        else             v[((size_t)bhn*DP + d)*NSEQ + n] = o;
      }
    }
  }
}

// ---------------- K2: flash attention, NO LDS / NO barriers ----------------
// K/V are L2-resident (768 KB/head, 16 blocks share a head). All MFMA fragments load
// DIRECTLY from global as coalesced 64B row-segments; the entire staging apparatus
// (LDS, XOR swizzle, double-buffer, 32 barrier drains) is deleted. Waves fully
// independent. 2-deep register prefetch with named sets (static indexing).
// XCD-bijective decode pins each head's 16 blocks to one XCD's L2 (3 MB working set).
__global__ __launch_bounds__(256, 2) void attn(const u16* __restrict__ q, const u16* __restrict__ k,
                                               const u16* __restrict__ v, u16* __restrict__ y){
#ifndef HAVE_PERMSWAP
  __shared__ __align__(16) u16 Pl[4*2*1024];    // fallback only
#endif
  const int lin = blockIdx.x;                   // 512 blocks
  const int xcd = lin & 7, jj = lin >> 3;       // assume wg->XCD round-robin (perf-only)
  const int bh  = xcd*4 + (jj >> 4);            // heads 4*xcd .. 4*xcd+3 on this XCD
  const int qt  = jj & 15;
  const int wave = threadIdx.x >> 6;
  const int lane = threadIdx.x & 63;
  const int l15  = lane & 15;
  const int quad = lane >> 4;
  const u16* qb = q + (size_t)bh*NSEQ*DP;
  const u16* kb = k + (size_t)bh*NSEQ*DP;
  const u16* vb = v + (size_t)bh*DP*NSEQ;
  const int qm = qt*128 + wave*32;

  v8s qf[2][2];                                 // [strip][ks]
#pragma unroll
  for (int si = 0; si < 2; si++)
#pragma unroll
    for (int ks = 0; ks < 2; ks++)
      qf[si][ks] = *(const v8s*)(qb + (size_t)(qm + si*16 + l15)*DP + ks*32 + quad*8);

  const short one = (short)0x3F80;
  const v8s vones = (l15 == 0) ? (v8s){one,one,one,one,one,one,one,one}
                               : (v8s){0,0,0,0,0,0,0,0};

  v4f o[2][4];                   // [strip][dt]; dt3 col0 = rowsum
#pragma unroll
  for (int si = 0; si < 2; si++)
#pragma unroll
    for (int i = 0; i < 4; i++) o[si][i] = (v4f){0.f,0.f,0.f,0.f};

  // direct-load fragment bases: lane(quad,l15) owns row l15, 16B granule quad
  const u16* kfb = kb + (size_t)l15*DP + quad*8;    // K[l15 + 16*nt + 64*t][quad*8 (+32)]
  const u16* vfb = vb + (size_t)l15*NSEQ + quad*8;  // V[l15 + 16*dt][t*64 + ks*32 + quad*8]

#ifndef HAVE_PERMSWAP
  u16* Plw = Pl + wave*2048;
#endif

  // load fragments for tile t_ into named register set (static indexing only)
#define LOADT(t_, K0_, K1_, VF_) do{                                                    \
    _Pragma("unroll")                                                                   \
    for (int nt = 0; nt < 4; nt++){                                                     \
      const u16* kp = kfb + (size_t)((t_)*64 + nt*16)*DP;                               \
      K0_[nt] = *(const v8s*)(kp);                                                      \
      K1_[nt] = *(const v8s*)(kp + 32);                                                 \
    }                                                                                   \
    _Pragma("unroll")                                                                   \
    for (int dt = 0; dt < 3; dt++)                                                      \
      _Pragma("unroll")                                                                 \
      for (int ks = 0; ks < 2; ks++)                                                    \
        VF_[dt*2+ks] = *(const v8s*)(vfb + (size_t)dt*16*NSEQ + (t_)*64 + ks*32);       \
  } while(0)

#ifdef HAVE_PERMSWAP
#define PTRANS                                                                          \
    _Pragma("unroll")                                                                   \
    for (int si = 0; si < 2; si++){                                                     \
      unsigned w[4][2];                                                                 \
      _Pragma("unroll")                                                                 \
      for (int nt = 0; nt < 4; nt++){                                                   \
        w[nt][0] = pkbf(EXP2(s[si][nt][0]), EXP2(s[si][nt][1]));                        \
        w[nt][1] = pkbf(EXP2(s[si][nt][2]), EXP2(s[si][nt][3]));                        \
      }                                                                                 \
      _Pragma("unroll")                                                                 \
      for (int ks = 0; ks < 2; ks++){                                                   \
        unsigned W[4];                                                                  \
        _Pragma("unroll")                                                               \
        for (int h = 0; h < 2; h++){                                                    \
          auto a = __builtin_amdgcn_permlane32_swap(w[2*ks][h], w[2*ks+1][h], false, false); \
          auto b = __builtin_amdgcn_permlane16_swap(a[0], a[1], false, false);          \
          W[h]   = b[0];                                                                \
          W[2+h] = b[1];                                                                \
        }                                                                               \
        uint4v u; u[0] = W[0]; u[1] = W[1]; u[2] = W[2]; u[3] = W[3];                   \
        pa[si][ks] = __builtin_bit_cast(v8s, u);                                        \
      }                                                                                 \
    }
#else
#define PTRANS                                                                          \
    _Pragma("unroll")                                                                   \
    for (int si = 0; si < 2; si++)                                                      \
      _Pragma("unroll")                                                                 \
      for (int nt = 0; nt < 4; nt++){                                                   \
        uint2v pw;                                                                      \
        pw.x = pkbf(EXP2(s[si][nt][0]), EXP2(s[si][nt][1]));                            \
        pw.y = pkbf(EXP2(s[si][nt][2]), EXP2(s[si][nt][3]));                            \
        int lo3 = l15 & 7;                                                              \
        int g = nt*2 + (quad>>1);                                                       \
        *(uint2v*)(&Plw[si*1024 + l15*64 + ((g ^ lo3)<<3) + (quad&1)*4]) = pw;          \
      }                                                                                 \
    __syncthreads();                                                                    \
    _Pragma("unroll")                                                                   \
    for (int si = 0; si < 2; si++)                                                      \
      _Pragma("unroll")                                                                 \
      for (int ks = 0; ks < 2; ks++){                                                   \
        int lo3 = l15 & 7;                                                              \
        int ga = ks*4 + quad;                                                           \
        pa[si][ks] = *(const v8s*)(&Plw[si*1024 + l15*64 + ((ga ^ lo3)<<3)]);           \
      }
#endif

#define COMPUTE(K0_, K1_, VF_) do{                                                      \
    v4f s[2][4];                                                                        \
    _Pragma("unroll")                                                                   \
    for (int nt = 0; nt < 4; nt++){                                                     \
      s[0][nt] = __builtin_amdgcn_mfma_f32_16x16x32_bf16(K0_[nt], qf[0][0], (v4f){0.f,0.f,0.f,0.f}, 0, 0, 0); \
      s[0][nt] = __builtin_amdgcn_mfma_f32_16x16x32_bf16(K1_[nt], qf[0][1], s[0][nt], 0, 0, 0); \
      s[1][nt] = __builtin_amdgcn_mfma_f32_16x16x32_bf16(K0_[nt], qf[1][0], (v4f){0.f,0.f,0.f,0.f}, 0, 0, 0); \
      s[1][nt] = __builtin_amdgcn_mfma_f32_16x16x32_bf16(K1_[nt], qf[1][1], s[1][nt], 0, 0, 0); \
    }                                                                                   \
    v8s pa[2][2];                                                                       \
    PTRANS                                                                              \
    _Pragma("unroll")                                                                   \
    for (int dt = 0; dt < 3; dt++){                                                     \
      _Pragma("unroll")                                                                 \
      for (int ks = 0; ks < 2; ks++){                                                   \
        o[0][dt] = __builtin_amdgcn_mfma_f32_16x16x32_bf16(pa[0][ks], VF_[dt*2+ks], o[0][dt], 0, 0, 0); \
        o[1][dt] = __builtin_amdgcn_mfma_f32_16x16x32_bf16(pa[1][ks], VF_[dt*2+ks], o[1][dt], 0, 0, 0); \
      }                                                                                 \
    }                                                                                   \
    _Pragma("unroll")                                                                   \
    for (int ks = 0; ks < 2; ks++){                                                     \
      o[0][3] = __builtin_amdgcn_mfma_f32_16x16x32_bf16(pa[0][ks], vones, o[0][3], 0, 0, 0); \
      o[1][3] = __builtin_amdgcn_mfma_f32_16x16x32_bf16(pa[1][ks], vones, o[1][3], 0, 0, 0); \
    }                                                                                   \
  } while(0)

  v8s k0A[4], k1A[4], vfA[6];
  v8s k0B[4], k1B[4], vfB[6];

  LOADT(0, k0A, k1A, vfA);
  for (int t = 0; t < 32; t += 2){
    LOADT(t + 1, k0B, k1B, vfB);                // in flight under COMPUTE(A)
    COMPUTE(k0A, k1A, vfA);
    if (t + 2 < 32) LOADT(t + 2, k0A, k1A, vfA);// in flight under COMPUTE(B)
    COMPUTE(k0B, k1B, vfB);
  }

  // epilogue: full rowsum lives at dt3 col0 (lanes with l15==0); broadcast within quad,
  // normalize, write y bf16 directly
  const int b_ = bh / NH, h = bh % NH;
#pragma unroll
  for (int si = 0; si < 2; si++){
#pragma unroll
    for (int r = 0; r < 4; r++){
      float l = __shfl(o[si][3][r], (lane & 48));   // from lane (quad*16 + 0)
      float inv = RCP(l);
      int rowg = b_*NSEQ + qm + si*16 + quad*4 + r;
#pragma unroll
      for (int dt = 0; dt < 3; dt++)
        y[(size_t)rowg*CDIM + h*DH + dt*16 + l15] = f2bf(o[si][dt][r]*inv);
    }
  }
#undef LOADT
#undef COMPUTE
#undef PTRANS
}

// ================= K3: proj GEMM, 64x64 tile, single-buffered m97 loop (round-10) =================
__global__ __launch_bounds__(256) void proj_gemm(const u16* __restrict__ y, const u16* __restrict__ w,
                                                 const float* __restrict__ bias, float* __restrict__ out){
  __shared__ __align__(16) u16 As[64*32];
  __shared__ __align__(16) u16 Bs[64*32];
  const int wave = threadIdx.x >> 6;
  const int lane = threadIdx.x & 63;
  const int l15  = lane & 15;
  const int quad = lane >> 4;
  const int wm = wave & 1, wn = wave >> 1;      // wn in {0,1}: 2 n-halves of 32
  const int m0 = blockIdx.x*64, n0 = blockIdx.y*64;

  const int srow = lane >> 2;
  const int sg   = (lane & 3) ^ ((lane >> 3) & 3);
  const int sgoff = sg*8;

  v4f acc[2][2];
#pragma unroll
  for (int i = 0; i < 2; i++)
#pragma unroll
    for (int j = 0; j < 2; j++) acc[i][j] = (v4f){0.f,0.f,0.f,0.f};

  const int sig = (l15 >> 1) & 3;
  const int rS = wave*16 + srow;                // staging row 0..63 (one A + one B load/thread)

  for (int kt = 0; kt < CDIM/32; kt++){
    const int k0 = kt*32;
    __syncthreads();
    load_lds16(y + (size_t)(m0 + rS)*CDIM + k0 + sgoff, &As[wave*512]);
    load_lds16(w + (size_t)(n0 + rS)*CDIM + k0 + sgoff, &Bs[wave*512]);
    __syncthreads();

    v8s af[2], bf[2];
#pragma unroll
    for (int t = 0; t < 2; t++){
      int ra = wm*32 + t*16 + l15;
      af[t] = *(const v8s*)(&As[ra*32 + ((quad ^ sig)<<3)]);
      int rb = wn*32 + t*16 + l15;
      bf[t] = *(const v8s*)(&Bs[rb*32 + ((quad ^ sig)<<3)]);
    }
#pragma unroll
    for (int ti = 0; ti < 2; ti++)
#pragma unroll
      for (int tj = 0; tj < 2; tj++)
        acc[ti][tj] = __builtin_amdgcn_mfma_f32_16x16x32_bf16(af[ti], bf[tj], acc[ti][tj], 0, 0, 0);
  }

#pragma unroll
  for (int tj = 0; tj < 2; tj++){
    const int c = n0 + wn*32 + tj*16 + l15;
    const float bv = bias[c];
#pragma unroll
    for (int ti = 0; ti < 2; ti++){
#pragma unroll
      for (int r = 0; r < 4; r++){
        int m = m0 + wm*32 + ti*16 + quad*4 + r;
        out[(size_t)m*CDIM + c] = acc[ti][tj][r] + bv;
      }
    }
  }
}

extern "C" void kernel_launch(void* const* d_in, const int* in_sizes, int n_in,
                              void* d_out, int out_size, void* d_ws, size_t ws_size,
                              hipStream_t stream){
  const float* x      = (const float*)d_in[0];
  const float* qkv_w  = (const float*)d_in[1];
  const float* qkv_b  = (const float*)d_in[2];
  const float* proj_w = (const float*)d_in[3];
  const float* proj_b = (const float*)d_in[4];
  float* out = (float*)d_out;

  // ws layout (u16 units); y reuses xb's region (x dead after qkv)
  u16* xb  = (u16*)d_ws;                         // [4096][768] bf16, later y
  u16* wb  = xb  + (size_t)MROWS*CDIM;           // [2304][768] bf16
  u16* pwb = wb  + (size_t)N3C*CDIM;             // [768][768]  bf16
  u16* q   = pwb + (size_t)CDIM*CDIM;            // [BH][NSEQ][DP]
  u16* k   = q + (size_t)BH*NSEQ*DP;
  u16* v   = k + (size_t)BH*NSEQ*DP;             // [BH][DP][NSEQ]
  u16* y = xb;

  prep<<<dim3(CONVB + 512), dim3(256), 0, stream>>>(x, qkv_w, proj_w, xb, q, k);
  qkv_gemm<<<dim3(MROWS/128, N3C/128), dim3(256), 0, stream>>>(xb, wb, qkv_b, q, k, v);
  attn<<<dim3(BH*NSEQ/128), dim3(256), 0, stream>>>(q, k, v, y);
  proj_gemm<<<dim3(MROWS/64, CDIM/64), dim3(256), 0, stream>>>(y, pwb, proj_b, out);
}

// Round 12
// 162.443 us; speedup vs baseline: 1.3613x; 1.3613x over previous
//
#include <hip/hip_runtime.h>

typedef short v8s __attribute__((ext_vector_type(8)));
typedef short v4s __attribute__((ext_vector_type(4)));
typedef float v4f __attribute__((ext_vector_type(4)));
typedef unsigned uint2v __attribute__((ext_vector_type(2)));
typedef unsigned uint4v __attribute__((ext_vector_type(4)));
typedef unsigned short u16;

#define NSEQ 2048
#define CDIM 768
#define NH   16
#define DH   48
#define DP   64
#define MROWS 4096      // B*N
#define N3C  2304
#define BH   32         // B*H

#if __has_builtin(__builtin_amdgcn_exp2f)
#define EXP2(x) __builtin_amdgcn_exp2f(x)
#else
#define EXP2(x) exp2f(x)
#endif
#if __has_builtin(__builtin_amdgcn_rcpf)
#define RCP(x) __builtin_amdgcn_rcpf(x)
#else
#define RCP(x) (1.0f/(x))
#endif

#if __has_builtin(__builtin_amdgcn_permlane32_swap) && __has_builtin(__builtin_amdgcn_permlane16_swap)
#define HAVE_PERMSWAP 1
#endif

__device__ __forceinline__ u16 f2bf(float f){
  unsigned u = __float_as_uint(f);
  u += 0x7FFFu + ((u>>16)&1u);      // RNE; inputs finite
  return (u16)(u>>16);
}

#if __has_builtin(__builtin_amdgcn_cvt_pk_bf16_f32)
typedef __bf16 bf16x2_t __attribute__((ext_vector_type(2)));
__device__ __forceinline__ unsigned pkbf(float a, float b){   // [lo=a, hi=b], RNE, 1 inst
  bf16x2_t r = __builtin_amdgcn_cvt_pk_bf16_f32(a, b);
  return __builtin_bit_cast(unsigned, r);
}
#else
__device__ __forceinline__ unsigned pkbf(float a, float b){   // [lo=a, hi=b] bf16 pair, RNE
  unsigned x = __float_as_uint(a), y = __float_as_uint(b);
  x += 0x7FFFu + ((x>>16)&1u);
  y += 0x7FFFu + ((y>>16)&1u);
  return (x>>16) | (y & 0xFFFF0000u);
}
#endif

__device__ __forceinline__ void load_lds16(const u16* g, u16* l){
  __builtin_amdgcn_global_load_lds((const __attribute__((address_space(1))) void*)g,
                                   (__attribute__((address_space(3))) void*)l, 16, 0, 0);
}

// ---------------- K0: fused convert (x,qkv_w,proj_w -> bf16) + Q/K pad init ----------------
#define XN8  (MROWS*CDIM/8)                     // 393216
#define WN8  (N3C*CDIM/8)                       // 221184
#define PN8  (CDIM*CDIM/8)                      // 73728
#define CONVB ((XN8+WN8+PN8)/256)               // 2688 blocks
__global__ __launch_bounds__(256) void prep(const float* __restrict__ x, const float* __restrict__ w,
                                            const float* __restrict__ pw, u16* __restrict__ dst,
                                            u16* __restrict__ q, u16* __restrict__ k){
  int bid = blockIdx.x;
  if (bid < CONVB){
    int i = bid*256 + threadIdx.x;
    const float* src;
    if (i < XN8)            src = x  + (size_t)i*8;
    else if (i < XN8+WN8)   src = w  + (size_t)(i - XN8)*8;
    else                    src = pw + (size_t)(i - XN8 - WN8)*8;
    v4f f0 = ((const v4f*)src)[0];
    v4f f1 = ((const v4f*)src)[1];
    v8s o;
#pragma unroll
    for (int j = 0; j < 4; j++) ((u16*)&o)[j]   = f2bf(f0[j]);
#pragma unroll
    for (int j = 0; j < 4; j++) ((u16*)&o)[4+j] = f2bf(f1[j]);
    ((v8s*)dst)[i] = o;
  } else {
    int idx = (bid - CONVB)*256 + threadIdx.x;  // 512 blocks -> 131072 threads
    v8s z = (v8s){0,0,0,0,0,0,0,0};
    int r = idx >> 1, half = idx & 1;           // Q/K: 65536 rows, 2x16B pad per row
    *(v8s*)(q + (size_t)r*DP + DH + half*8) = z;
    *(v8s*)(k + (size_t)r*DP + DH + half*8) = z;
  }
}

// ================= K1: qkv GEMM, m97 structure, 128x96 tile (768 blocks = 3/CU uniform) =================
// Same BK=32 2-barrier loop/swizzle as round-4; only the N-tile changed (128 -> 96) to
// remove the 2.25-blocks/CU makespan tail. Per wave: 64x48 output, acc[4][3].
__global__ __launch_bounds__(256) void qkv_gemm(const u16* __restrict__ x, const u16* __restrict__ w,
                                                const float* __restrict__ bias,
                                                u16* __restrict__ q, u16* __restrict__ k, u16* __restrict__ v){
  __shared__ __align__(16) u16 As[128*32];
  __shared__ __align__(16) u16 Bs[96*32];
  const int wave = threadIdx.x >> 6;
  const int lane = threadIdx.x & 63;
  const int l15  = lane & 15;
  const int quad = lane >> 4;
  const int wm = wave & 1, wn = wave >> 1;
  const int m0 = blockIdx.x*128, n0 = blockIdx.y*96;

  const int srow = lane >> 2;
  const int sg   = (lane & 3) ^ ((lane >> 3) & 3);
  const int sgoff = sg*8;

  v4f acc[4][3];
#pragma unroll
  for (int i = 0; i < 4; i++)
#pragma unroll
    for (int j = 0; j < 3; j++) acc[i][j] = (v4f){0.f,0.f,0.f,0.f};

  const int sig = (l15 >> 1) & 3;

  for (int kt = 0; kt < CDIM/32; kt++){
    const int k0 = kt*32;
    __syncthreads();
#pragma unroll
    for (int j = 0; j < 2; j++){
      int c = wave*2 + j;
      int r = c*16 + srow;
      load_lds16(x + (size_t)(m0 + r)*CDIM + k0 + sgoff, &As[c*512]);
    }
    {
      int rB = wave*16 + srow;
      load_lds16(w + (size_t)(n0 + rB)*CDIM + k0 + sgoff, &Bs[wave*512]);
    }
    if (wave < 2){
      int cB = 4 + wave;
      int rB = cB*16 + srow;
      load_lds16(w + (size_t)(n0 + rB)*CDIM + k0 + sgoff, &Bs[cB*512]);
    }
    __syncthreads();

    v8s af[4], bf[3];
#pragma unroll
    for (int t = 0; t < 4; t++){
      int ra = wm*64 + t*16 + l15;
      af[t] = *(const v8s*)(&As[ra*32 + ((quad ^ sig)<<3)]);
    }
#pragma unroll
    for (int t = 0; t < 3; t++){
      int rb = wn*48 + t*16 + l15;
      bf[t] = *(const v8s*)(&Bs[rb*32 + ((quad ^ sig)<<3)]);
    }
#pragma unroll
    for (int ti = 0; ti < 4; ti++)
#pragma unroll
      for (int tj = 0; tj < 3; tj++)
        acc[ti][tj] = __builtin_amdgcn_mfma_f32_16x16x32_bf16(af[ti], bf[tj], acc[ti][tj], 0, 0, 0);
  }

  const float QS = 0.2082540589f;   // 1/sqrt(48) * log2(e)
#pragma unroll
  for (int tj = 0; tj < 3; tj++){
    const int c = n0 + wn*48 + tj*16 + l15;
    const float bv = bias[c];
    const int t = c / CDIM;
    const int rem = c - t*CDIM;
    const int h = rem / DH;
    const int d = rem - h*DH;
#pragma unroll
    for (int ti = 0; ti < 4; ti++){
#pragma unroll
      for (int r = 0; r < 4; r++){
        int m = m0 + wm*64 + ti*16 + quad*4 + r;
        int b_ = m >> 11;
        int n  = m & (NSEQ-1);
        float val = acc[ti][tj][r] + bv;
        if (t == 0) val *= QS;
        u16 o  = f2bf(val);
        int bhn = b_*NH + h;
        if (t == 0)      q[((size_t)bhn*NSEQ + n)*DP + d] = o;
        else if (t == 1) k[((size_t)bhn*NSEQ + n)*DP + d] = o;
        else             v[((size_t)bhn*DP + d)*NSEQ + n] = o;
      }
    }
  }
}

// ---------------- K2: flash attention, full key range per block, direct y output (round-4) ----------------
// P never touches LDS (permlane transpose). No key-split: each block sees all 2048 keys,
// so the softmax denominator is complete in-register -> normalize + write y bf16 directly.
__global__ __launch_bounds__(256, 4) void attn(const u16* __restrict__ q, const u16* __restrict__ k,
                                               const u16* __restrict__ v, u16* __restrict__ y){
  __shared__ __align__(16) u16 Kl[2][64*64];    // 2x8 KB, [key][d] XOR-swizzled
  __shared__ __align__(16) u16 Vl[2][48*64];    // 2x6 KB, [d][key] rows 0..47
#ifndef HAVE_PERMSWAP
  __shared__ __align__(16) u16 Pl[4*2*1024];    // fallback only
#endif
  const int bh = blockIdx.x;
  const int qt = blockIdx.y;                    // 128-row Q tile
  const int wave = threadIdx.x >> 6;
  const int lane = threadIdx.x & 63;
  const int l15  = lane & 15;
  const int quad = lane >> 4;
  const int lo3  = l15 & 7;
  const u16* qb = q + (size_t)bh*NSEQ*DP;
  const u16* kb = k + (size_t)bh*NSEQ*DP;
  const u16* vb = v + (size_t)bh*DP*NSEQ;
  const int qm = qt*128 + wave*32;

  v8s qf[2][2];                                 // [strip][ks]
#pragma unroll
  for (int si = 0; si < 2; si++)
#pragma unroll
    for (int ks = 0; ks < 2; ks++)
      qf[si][ks] = *(const v8s*)(qb + (size_t)(qm + si*16 + l15)*DP + ks*32 + quad*8);

  const short one = (short)0x3F80;
  const v8s vones = (l15 == 0) ? (v8s){one,one,one,one,one,one,one,one}
                               : (v8s){0,0,0,0,0,0,0,0};

  v4f o[2][4];                   // [strip][dt]; dt3 col0 = rowsum
#pragma unroll
  for (int si = 0; si < 2; si++)
#pragma unroll
    for (int i = 0; i < 4; i++) o[si][i] = (v4f){0.f,0.f,0.f,0.f};

  const int sr  = lane >> 3;                    // 0..7
  const int soff = ((lane & 7) ^ (sr & 7)) * 8; // permuted 16B granule
#ifndef HAVE_PERMSWAP
  u16* Plw = Pl + wave*2048;
#endif

  // stage key-tile kt into buffer b (async DMA; no wait here)
  const int krow0 = wave*8 + sr;
#define STAGE(kt_, b_) do{                                                              \
    load_lds16(kb + ((size_t)((kt_)*64 + krow0))*DP + soff,      &Kl[b_][krow0*64]);    \
    load_lds16(kb + ((size_t)((kt_)*64 + 32 + krow0))*DP + soff, &Kl[b_][(32+krow0)*64]);\
    load_lds16(vb + (size_t)krow0*NSEQ + (kt_)*64 + soff,        &Vl[b_][krow0*64]);    \
    if (wave < 2)                                                                       \
      load_lds16(vb + (size_t)(32+krow0)*NSEQ + (kt_)*64 + soff, &Vl[b_][(32+krow0)*64]);\
  } while(0)

  STAGE(0, 0);

  for (int i = 0; i < 32; i++){
    const int buf = i & 1;
    __syncthreads();                            // publishes buf; drains are overlapped by compute
    if (i < 31) STAGE(i + 1, buf^1);            // prefetch next tile into other buffer

    const u16* Klb = &Kl[buf][0];
    const u16* Vlb = &Vl[buf][0];

    // S^T = K Q^T for both strips; each K fragment read once
    v4f s[2][4];
#pragma unroll
    for (int nt = 0; nt < 4; nt++){
      int rrow = nt*16 + l15;
      v8s kf0 = *(const v8s*)(&Klb[rrow*64 + ((quad ^ lo3)<<3)]);
      v8s kf1 = *(const v8s*)(&Klb[rrow*64 + (((4+quad) ^ lo3)<<3)]);
      s[0][nt] = __builtin_amdgcn_mfma_f32_16x16x32_bf16(kf0, qf[0][0], (v4f){0.f,0.f,0.f,0.f}, 0, 0, 0);
      s[0][nt] = __builtin_amdgcn_mfma_f32_16x16x32_bf16(kf1, qf[0][1], s[0][nt], 0, 0, 0);
      s[1][nt] = __builtin_amdgcn_mfma_f32_16x16x32_bf16(kf0, qf[1][0], (v4f){0.f,0.f,0.f,0.f}, 0, 0, 0);
      s[1][nt] = __builtin_amdgcn_mfma_f32_16x16x32_bf16(kf1, qf[1][1], s[1][nt], 0, 0, 0);
    }

    // P = exp2(S^T); redistribute to PV A-fragments
    v8s pa[2][2];                               // [strip][ks]
#ifdef HAVE_PERMSWAP
#pragma unroll
    for (int si = 0; si < 2; si++){
      // lane(quad,l15) holds P[q=l15][key = nt*16 + quad*4 + r]; pack key-pairs
      unsigned w[4][2];
#pragma unroll
      for (int nt = 0; nt < 4; nt++){
        w[nt][0] = pkbf(EXP2(s[si][nt][0]), EXP2(s[si][nt][1]));
        w[nt][1] = pkbf(EXP2(s[si][nt][2]), EXP2(s[si][nt][3]));
      }
      // 32swap(A,B): [A0,A1,B0,B1],[A2,A3,B2,B3]; 16swap of those: [A0,A2,B0,B2],[A1,A3,B1,B3]
#pragma unroll
      for (int ks = 0; ks < 2; ks++){
        unsigned W[4];
#pragma unroll
        for (int h = 0; h < 2; h++){
          auto a = __builtin_amdgcn_permlane32_swap(w[2*ks][h], w[2*ks+1][h], false, false);
          auto b = __builtin_amdgcn_permlane16_swap(a[0], a[1], false, false);
          W[h]   = b[0];
          W[2+h] = b[1];
        }
        uint4v u; u[0] = W[0]; u[1] = W[1]; u[2] = W[2]; u[3] = W[3];
        pa[si][ks] = __builtin_bit_cast(v8s, u);
      }
    }
#else
    // fallback: P round-trip through LDS (original path)
#pragma unroll
    for (int si = 0; si < 2; si++)
#pragma unroll
      for (int nt = 0; nt < 4; nt++){
        uint2v pw;
        pw.x = pkbf(EXP2(s[si][nt][0]), EXP2(s[si][nt][1]));
        pw.y = pkbf(EXP2(s[si][nt][2]), EXP2(s[si][nt][3]));
        int g = nt*2 + (quad>>1);
        *(uint2v*)(&Plw[si*1024 + l15*64 + ((g ^ lo3)<<3) + (quad&1)*4]) = pw;
      }
    __syncthreads();
#pragma unroll
    for (int si = 0; si < 2; si++)
#pragma unroll
      for (int ks = 0; ks < 2; ks++){
        int ga = ks*4 + quad;
        pa[si][ks] = *(const v8s*)(&Plw[si*1024 + l15*64 + ((ga ^ lo3)<<3)]);
      }
#endif

    // O += P V  (V fragments shared by both strips); dt3 via constant ones-frag
#pragma unroll
    for (int dt = 0; dt < 3; dt++){
#pragma unroll
      for (int ks = 0; ks < 2; ks++){
        int row = dt*16 + l15;
        v8s vf = *(const v8s*)(&Vlb[row*64 + (((ks*4+quad) ^ lo3)<<3)]);
        o[0][dt] = __builtin_amdgcn_mfma_f32_16x16x32_bf16(pa[0][ks], vf, o[0][dt], 0, 0, 0);
        o[1][dt] = __builtin_amdgcn_mfma_f32_16x16x32_bf16(pa[1][ks], vf, o[1][dt], 0, 0, 0);
      }
    }
#pragma unroll
    for (int ks = 0; ks < 2; ks++){
      o[0][3] = __builtin_amdgcn_mfma_f32_16x16x32_bf16(pa[0][ks], vones, o[0][3], 0, 0, 0);
      o[1][3] = __builtin_amdgcn_mfma_f32_16x16x32_bf16(pa[1][ks], vones, o[1][3], 0, 0, 0);
    }
  }

  // epilogue: full rowsum lives at dt3 col0 (lanes with l15==0); broadcast within quad,
  // normalize, write y bf16 directly
  const int b_ = bh / NH, h = bh % NH;
#pragma unroll
  for (int si = 0; si < 2; si++){
#pragma unroll
    for (int r = 0; r < 4; r++){
      float l = __shfl(o[si][3][r], (lane & 48));   // from lane (quad*16 + 0)
      float inv = RCP(l);
      int rowg = b_*NSEQ + qm + si*16 + quad*4 + r;
#pragma unroll
      for (int dt = 0; dt < 3; dt++)
        y[(size_t)rowg*CDIM + h*DH + dt*16 + l15] = f2bf(o[si][dt][r]*inv);
    }
  }
#undef STAGE
}

// ================= K3: proj GEMM, 64x64 tile, single-buffered m97 loop (round-10) =================
__global__ __launch_bounds__(256) void proj_gemm(const u16* __restrict__ y, const u16* __restrict__ w,
                                                 const float* __restrict__ bias, float* __restrict__ out){
  __shared__ __align__(16) u16 As[64*32];
  __shared__ __align__(16) u16 Bs[64*32];
  const int wave = threadIdx.x >> 6;
  const int lane = threadIdx.x & 63;
  const int l15  = lane & 15;
  const int quad = lane >> 4;
  const int wm = wave & 1, wn = wave >> 1;      // wn in {0,1}: 2 n-halves of 32
  const int m0 = blockIdx.x*64, n0 = blockIdx.y*64;

  const int srow = lane >> 2;
  const int sg   = (lane & 3) ^ ((lane >> 3) & 3);
  const int sgoff = sg*8;

  v4f acc[2][2];
#pragma unroll
  for (int i = 0; i < 2; i++)
#pragma unroll
    for (int j = 0; j < 2; j++) acc[i][j] = (v4f){0.f,0.f,0.f,0.f};

  const int sig = (l15 >> 1) & 3;
  const int rS = wave*16 + srow;                // staging row 0..63 (one A + one B load/thread)

  for (int kt = 0; kt < CDIM/32; kt++){
    const int k0 = kt*32;
    __syncthreads();
    load_lds16(y + (size_t)(m0 + rS)*CDIM + k0 + sgoff, &As[wave*512]);
    load_lds16(w + (size_t)(n0 + rS)*CDIM + k0 + sgoff, &Bs[wave*512]);
    __syncthreads();

    v8s af[2], bf[2];
#pragma unroll
    for (int t = 0; t < 2; t++){
      int ra = wm*32 + t*16 + l15;
      af[t] = *(const v8s*)(&As[ra*32 + ((quad ^ sig)<<3)]);
      int rb = wn*32 + t*16 + l15;
      bf[t] = *(const v8s*)(&Bs[rb*32 + ((quad ^ sig)<<3)]);
    }
#pragma unroll
    for (int ti = 0; ti < 2; ti++)
#pragma unroll
      for (int tj = 0; tj < 2; tj++)
        acc[ti][tj] = __builtin_amdgcn_mfma_f32_16x16x32_bf16(af[ti], bf[tj], acc[ti][tj], 0, 0, 0);
  }

#pragma unroll
  for (int tj = 0; tj < 2; tj++){
    const int c = n0 + wn*32 + tj*16 + l15;
    const float bv = bias[c];
#pragma unroll
    for (int ti = 0; ti < 2; ti++){
#pragma unroll
      for (int r = 0; r < 4; r++){
        int m = m0 + wm*32 + ti*16 + quad*4 + r;
        out[(size_t)m*CDIM + c] = acc[ti][tj][r] + bv;
      }
    }
  }
}

extern "C" void kernel_launch(void* const* d_in, const int* in_sizes, int n_in,
                              void* d_out, int out_size, void* d_ws, size_t ws_size,
                              hipStream_t stream){
  const float* x      = (const float*)d_in[0];
  const float* qkv_w  = (const float*)d_in[1];
  const float* qkv_b  = (const float*)d_in[2];
  const float* proj_w = (const float*)d_in[3];
  const float* proj_b = (const float*)d_in[4];
  float* out = (float*)d_out;

  // ws layout (u16 units); y reuses xb's region (x dead after qkv)
  u16* xb  = (u16*)d_ws;                         // [4096][768] bf16, later y
  u16* wb  = xb  + (size_t)MROWS*CDIM;           // [2304][768] bf16
  u16* pwb = wb  + (size_t)N3C*CDIM;             // [768][768]  bf16
  u16* q   = pwb + (size_t)CDIM*CDIM;            // [BH][NSEQ][DP]
  u16* k   = q + (size_t)BH*NSEQ*DP;
  u16* v   = k + (size_t)BH*NSEQ*DP;             // [BH][DP][NSEQ]
  u16* y = xb;

  prep<<<dim3(CONVB + 512), dim3(256), 0, stream>>>(x, qkv_w, proj_w, xb, q, k);
  qkv_gemm<<<dim3(MROWS/128, N3C/96), dim3(256), 0, stream>>>(xb, wb, qkv_b, q, k, v);
  attn<<<dim3(BH, NSEQ/128), dim3(256), 0, stream>>>(q, k, v, y);
  proj_gemm<<<dim3(MROWS/64, CDIM/64), dim3(256), 0, stream>>>(y, pwb, proj_b, out);
}